// Round 2
// baseline (1525.530 us; speedup 1.0000x reference)
//
#include <hip/hip_runtime.h>

#define NMOV 100000
#define NUSR 50000
#define NN   150000
#define DIM  128
#define HID  256
#define NE   500000

// ---------------- degree count ----------------
__global__ __launch_bounds__(256) void deg_kernel(const int* __restrict__ dst,
                                                  float* __restrict__ deg) {
  int e = blockIdx.x * 256 + threadIdx.x;
  if (e < NE) atomicAdd(&deg[dst[e]], 1.0f);
}

__global__ __launch_bounds__(256) void invdeg_kernel(const float* __restrict__ deg,
                                                     float* __restrict__ invdeg) {
  int i = blockIdx.x * 256 + threadIdx.x;
  if (i < NN) invdeg[i] = 1.0f / fmaxf(deg[i], 1.0f);
}

// ---------------- layer-1 aggregation: acc[dst] += x[src]  (acc lives in d_out) --------
__global__ __launch_bounds__(256) void agg1_kernel(const int* __restrict__ src,
                                                   const int* __restrict__ dst,
                                                   const float* __restrict__ movie,
                                                   const float* __restrict__ user,
                                                   float* __restrict__ acc) {
  int i = blockIdx.x * 256 + threadIdx.x;   // NE*DIM = 64M threads, exact grid
  int e = i >> 7;
  int t = i & (DIM - 1);
  int s = src[e];
  int d = dst[e];
  const float* xrow = (s < NMOV) ? (movie + (size_t)s * DIM)
                                 : (user + (size_t)(s - NMOV) * DIM);
  atomicAdd(&acc[(size_t)d * DIM + t], xrow[t]);
}

// ---------------- fused: both layer GEMMs, h never leaves LDS ----------------
// Per 16-row tile:
//   a = acc_tile * invdeg  ; x = emb_tile
//   h = relu(a @ Wl1 + bl1 + x @ Wr1)              [16 x 256]  (LDS only)
//   hW  = h @ Wl2                                  [16 x 128]  -> ws
//   dref_tile = bl2 + h @ Wr2                      [16 x 128]  -> overwrite acc tile
// In-place overwrite of dref is safe: each block reads only its OWN 16 rows
// (into LDS, before the first __syncthreads) and writes only those rows.
__global__ __launch_bounds__(256) void fused_kernel(float* __restrict__ dref,
                                                    const float* __restrict__ movie,
                                                    const float* __restrict__ user,
                                                    const float* __restrict__ invdeg,
                                                    const float* __restrict__ Wl1,
                                                    const float* __restrict__ bl1,
                                                    const float* __restrict__ Wr1,
                                                    const float* __restrict__ Wl2,
                                                    const float* __restrict__ bl2,
                                                    const float* __restrict__ Wr2,
                                                    float* __restrict__ hW) {
  __shared__ float a_s[16][DIM];
  __shared__ float x_s[16][DIM];
  __shared__ float h_s[16][HID];
  __shared__ float inv_s[16];
  const int tid = threadIdx.x;
  const int row0 = blockIdx.x * 16;

  if (tid < 16) inv_s[tid] = invdeg[row0 + tid];
  __syncthreads();

  // stage 16x128 scaled agg + 16x128 x (float4)
  for (int idx = tid; idx < 16 * DIM / 4; idx += 256) {
    int r  = idx >> 5;
    int k4 = idx & 31;
    int row = row0 + r;
    float4 av = ((const float4*)(dref + (size_t)row * DIM))[k4];
    float iv = inv_s[r];
    av.x *= iv; av.y *= iv; av.z *= iv; av.w *= iv;
    ((float4*)&a_s[r][0])[k4] = av;
    const float* xrow = (row < NMOV) ? (movie + (size_t)row * DIM)
                                     : (user + (size_t)(row - NMOV) * DIM);
    ((float4*)&x_s[r][0])[k4] = ((const float4*)xrow)[k4];
  }
  __syncthreads();

  // ---- stage 1: h = relu(a@Wl1 + bl1 + x@Wr1), h -> LDS ----
  {
    const int j0 = (tid & 63) * 4;      // 256 cols / 4
    const int rb = (tid >> 6) * 4;      // wave-uniform row group -> LDS broadcast
    float acc[4][4];
#pragma unroll
    for (int i = 0; i < 4; i++)
#pragma unroll
      for (int c = 0; c < 4; c++) acc[i][c] = 0.0f;

    for (int k = 0; k < DIM; k++) {
      float4 wl = *(const float4*)(Wl1 + (size_t)k * HID + j0);
      float4 wr = *(const float4*)(Wr1 + (size_t)k * HID + j0);
#pragma unroll
      for (int i = 0; i < 4; i++) {
        float aL = a_s[rb + i][k];
        float aX = x_s[rb + i][k];
        acc[i][0] += aL * wl.x + aX * wr.x;
        acc[i][1] += aL * wl.y + aX * wr.y;
        acc[i][2] += aL * wl.z + aX * wr.z;
        acc[i][3] += aL * wl.w + aX * wr.w;
      }
    }
    float4 bv = *(const float4*)(bl1 + j0);
#pragma unroll
    for (int i = 0; i < 4; i++) {
      float4 o;
      o.x = fmaxf(acc[i][0] + bv.x, 0.0f);
      o.y = fmaxf(acc[i][1] + bv.y, 0.0f);
      o.z = fmaxf(acc[i][2] + bv.z, 0.0f);
      o.w = fmaxf(acc[i][3] + bv.w, 0.0f);
      ((float4*)&h_s[rb + i][0])[j0 >> 2] = o;
    }
  }
  __syncthreads();

  // ---- stage 2: hW = h@Wl2 ; dref = bl2 + h@Wr2 ----
  {
    const int j0 = (tid & 31) * 4;      // 128 cols / 4
    const int rb = (tid >> 5) * 2;      // 8 groups x 2 rows
    float accL[2][4], accR[2][4];
#pragma unroll
    for (int i = 0; i < 2; i++)
#pragma unroll
      for (int c = 0; c < 4; c++) { accL[i][c] = 0.0f; accR[i][c] = 0.0f; }

    for (int k = 0; k < HID; k++) {
      float4 wl = *(const float4*)(Wl2 + (size_t)k * DIM + j0);
      float4 wr = *(const float4*)(Wr2 + (size_t)k * DIM + j0);
#pragma unroll
      for (int i = 0; i < 2; i++) {
        float hv = h_s[rb + i][k];
        accL[i][0] += hv * wl.x; accR[i][0] += hv * wr.x;
        accL[i][1] += hv * wl.y; accR[i][1] += hv * wr.y;
        accL[i][2] += hv * wl.z; accR[i][2] += hv * wr.z;
        accL[i][3] += hv * wl.w; accR[i][3] += hv * wr.w;
      }
    }
    float4 bv = *(const float4*)(bl2 + j0);
#pragma unroll
    for (int i = 0; i < 2; i++) {
      int row = row0 + rb + i;
      float4 l;
      l.x = accL[i][0]; l.y = accL[i][1]; l.z = accL[i][2]; l.w = accL[i][3];
      ((float4*)(hW + (size_t)row * DIM))[j0 >> 2] = l;
      float4 o;
      o.x = accR[i][0] + bv.x;
      o.y = accR[i][1] + bv.y;
      o.z = accR[i][2] + bv.z;
      o.w = accR[i][3] + bv.w;
      ((float4*)(dref + (size_t)row * DIM))[j0 >> 2] = o;
    }
  }
}

// ---------------- layer-2 scatter: dref[dst] += hW[src] * invdeg[dst] ----------------
__global__ __launch_bounds__(256) void scatter2_kernel(const int* __restrict__ src,
                                                       const int* __restrict__ dst,
                                                       const float* __restrict__ hW,
                                                       const float* __restrict__ invdeg,
                                                       float* __restrict__ dref) {
  int i = blockIdx.x * 256 + threadIdx.x;   // NE*DIM = 64M threads, exact grid
  int e = i >> 7;
  int t = i & (DIM - 1);
  int s = src[e];
  int d = dst[e];
  atomicAdd(&dref[(size_t)d * DIM + t], hW[(size_t)s * DIM + t] * invdeg[d]);
}

// ---------------- edge scoring: out[e] = dot(refined[src], refined[dst]) ----------------
__global__ __launch_bounds__(256) void score_kernel(const int* __restrict__ src,
                                                    const int* __restrict__ dst,
                                                    const float* __restrict__ refined,
                                                    float* __restrict__ out) {
  int gid = blockIdx.x * 256 + threadIdx.x;
  int e = gid >> 6;
  int lane = threadIdx.x & 63;
  if (e >= NE) return;
  int s = src[e];
  int d = dst[e];
  float2 a = ((const float2*)(refined + (size_t)s * DIM))[lane];
  float2 b = ((const float2*)(refined + (size_t)d * DIM))[lane];
  float sum = a.x * b.x + a.y * b.y;
#pragma unroll
  for (int off = 1; off < 64; off <<= 1) sum += __shfl_xor(sum, off, 64);
  if (lane == 0) out[e] = sum;
}

extern "C" void kernel_launch(void* const* d_in, const int* in_sizes, int n_in,
                              void* d_out, int out_size, void* d_ws, size_t ws_size,
                              hipStream_t stream) {
  const int* ei    = (const int*)d_in[0];
  const int* src   = ei;
  const int* dst   = ei + NE;
  // d_in[1] = edge_attr (unused by the reference)
  const float* movie = (const float*)d_in[2];
  const float* user  = (const float*)d_in[3];
  const float* Wl1   = (const float*)d_in[4];
  const float* bl1   = (const float*)d_in[5];
  const float* Wr1   = (const float*)d_in[6];
  const float* Wl2   = (const float*)d_in[7];
  const float* bl2   = (const float*)d_in[8];
  const float* Wr2   = (const float*)d_in[9];

  float* out  = (float*)d_out;       // [NE] ratings
  float* dref = out + NE;            // [NN*DIM] refined (also layer-1 accumulator)

  // workspace: deg [NN] + invdeg [NN] + hW [NN*DIM]  = 78.0 MB total
  float* ws     = (float*)d_ws;
  float* deg    = ws;
  float* invdeg = deg + NN;
  float* hW     = invdeg + NN;

  hipMemsetAsync(deg, 0, (size_t)NN * sizeof(float), stream);
  hipMemsetAsync(dref, 0, (size_t)NN * DIM * sizeof(float), stream);

  deg_kernel<<<(NE + 255) / 256, 256, 0, stream>>>(dst, deg);
  invdeg_kernel<<<(NN + 255) / 256, 256, 0, stream>>>(deg, invdeg);
  agg1_kernel<<<NE * DIM / 256, 256, 0, stream>>>(src, dst, movie, user, dref);
  fused_kernel<<<NN / 16, 256, 0, stream>>>(dref, movie, user, invdeg,
                                            Wl1, bl1, Wr1, Wl2, bl2, Wr2, hW);
  scatter2_kernel<<<NE * DIM / 256, 256, 0, stream>>>(src, dst, hW, invdeg, dref);
  score_kernel<<<(NE * 64 + 255) / 256, 256, 0, stream>>>(src, dst, dref, out);
}

// Round 3
// 1074.559 us; speedup vs baseline: 1.4197x; 1.4197x over previous
//
#include <hip/hip_runtime.h>

#define NMOV 100000
#define NUSR 50000
#define NN   150000
#define DIM  128
#define HID  256
#define NE   500000

#define MBLK 64            // rows per block (4 waves x 16 rows)
#define LDK  264           // LDS row stride in shorts (256 + 8 pad -> conflict-free b128)

typedef __attribute__((ext_vector_type(8))) short bf16x8;
typedef __attribute__((ext_vector_type(4))) float f32x4;

__device__ __forceinline__ short f2bf(float f) {
  union { float f; unsigned u; } v; v.f = f;
  unsigned r = (v.u + 0x7fffu + ((v.u >> 16) & 1u)) >> 16;   // RNE
  return (short)r;
}

// ---------------- degree count ----------------
__global__ __launch_bounds__(256) void deg_kernel(const int* __restrict__ dst,
                                                  float* __restrict__ deg) {
  int e = blockIdx.x * 256 + threadIdx.x;
  if (e < NE) atomicAdd(&deg[dst[e]], 1.0f);
}

// in-place: deg[i] -> 1/max(deg[i],1)
__global__ __launch_bounds__(256) void invdeg_kernel(float* __restrict__ deg) {
  int i = blockIdx.x * 256 + threadIdx.x;
  if (i < NN) deg[i] = 1.0f / fmaxf(deg[i], 1.0f);
}

// ---------------- layer-1 aggregation: acc[dst] += x[src]  (acc lives in d_out) --------
__global__ __launch_bounds__(256) void agg1_kernel(const int* __restrict__ src,
                                                   const int* __restrict__ dst,
                                                   const float* __restrict__ movie,
                                                   const float* __restrict__ user,
                                                   float* __restrict__ acc) {
  int i = blockIdx.x * 256 + threadIdx.x;   // NE*DIM threads, exact grid
  int e = i >> 7;
  int t = i & (DIM - 1);
  int s = src[e];
  int d = dst[e];
  const float* xrow = (s < NMOV) ? (movie + (size_t)s * DIM)
                                 : (user + (size_t)(s - NMOV) * DIM);
  atomicAdd(&acc[(size_t)d * DIM + t], xrow[t]);
}

// ---------------- weight conversion: bf16, transposed, concatenated ----------------
// Wt1[n][k], n,k in [0,256): k<128 -> Wl1[k][n], else Wr1[k-128][n]
// Wt2[n][k]: n<128 -> Wl2[k][n] (hW cols), n>=128 -> Wr2[k][n-128] (dref cols)
__global__ __launch_bounds__(256) void convw_kernel(const float* __restrict__ Wl1,
                                                    const float* __restrict__ Wr1,
                                                    const float* __restrict__ Wl2,
                                                    const float* __restrict__ Wr2,
                                                    short* __restrict__ Wt1,
                                                    short* __restrict__ Wt2) {
  int idx = blockIdx.x * 256 + threadIdx.x;   // 2*65536 threads
  int half = idx >> 16;
  int j = idx & 65535;
  int n = j >> 8;
  int k = j & 255;
  if (half == 0) {
    float v = (k < 128) ? Wl1[(size_t)k * HID + n] : Wr1[(size_t)(k - 128) * HID + n];
    Wt1[j] = f2bf(v);
  } else {
    float v = (n < 128) ? Wl2[(size_t)k * DIM + n] : Wr2[(size_t)k * DIM + (n - 128)];
    Wt2[j] = f2bf(v);
  }
}

// ---------------- fused MFMA: both layer GEMMs, h never leaves LDS ----------------
// Per 64-row block (4 waves, wave owns 16 rows):
//   stage A_cat = [agg*inv | x] -> LDS bf16 [64][LDK]
//   stage1: h = relu(A_cat @ Wt1^T + bl1) -> written back into the wave's own LDS rows
//   stage2: [hW | dref] = h @ Wt2^T (+bl2 on dref half) -> global f32
__global__ __launch_bounds__(256, 2) void fused_mfma_kernel(
    float* __restrict__ dref, const float* __restrict__ movie,
    const float* __restrict__ user, const float* __restrict__ invdeg,
    const short* __restrict__ Wt1, const float* __restrict__ bl1,
    const short* __restrict__ Wt2, const float* __restrict__ bl2,
    float* __restrict__ hW) {
  __shared__ short tile[MBLK][LDK];
  __shared__ float inv_s[MBLK];
  const int tid = threadIdx.x;
  const int row0 = blockIdx.x * MBLK;

  if (tid < MBLK) {
    int row = row0 + tid;
    inv_s[tid] = (row < NN) ? invdeg[row] : 0.0f;
  }
  __syncthreads();

  // stage A_cat as bf16 (float4 global loads, short4 LDS stores)
  for (int idx = tid; idx < MBLK * 64; idx += 256) {
    int r  = idx >> 6;
    int c4 = idx & 63;
    int row = row0 + r;
    float4 v = make_float4(0.f, 0.f, 0.f, 0.f);
    int col;
    if (c4 < 32) {
      col = c4 * 4;
      if (row < NN) {
        v = ((const float4*)(dref + (size_t)row * DIM))[c4];
        float iv = inv_s[r];
        v.x *= iv; v.y *= iv; v.z *= iv; v.w *= iv;
      }
    } else {
      col = 128 + (c4 - 32) * 4;
      if (row < NN) {
        const float* xrow = (row < NMOV) ? (movie + (size_t)row * DIM)
                                         : (user + (size_t)(row - NMOV) * DIM);
        v = ((const float4*)xrow)[c4 - 32];
      }
    }
    short4 s4;
    s4.x = f2bf(v.x); s4.y = f2bf(v.y); s4.z = f2bf(v.z); s4.w = f2bf(v.w);
    *(short4*)&tile[r][col] = s4;
  }
  __syncthreads();

  const int lane = tid & 63;
  const int wv   = tid >> 6;
  const int c    = lane & 15;
  const int quad = lane >> 4;
  const int wrow = wv * 16;          // wave-owned rows [wrow, wrow+16)

  // ---- stage 1 ----
  {
    bf16x8 af[8];
#pragma unroll
    for (int kk = 0; kk < 8; kk++)
      af[kk] = *(const bf16x8*)&tile[wrow + c][kk * 32 + quad * 8];

#pragma unroll
    for (int n = 0; n < 16; n++) {
      f32x4 acc = {0.f, 0.f, 0.f, 0.f};
#pragma unroll
      for (int kk = 0; kk < 8; kk++) {
        bf16x8 bf = *(const bf16x8*)(Wt1 + ((size_t)(n * 16 + c) * 256 + kk * 32 + quad * 8));
        acc = __builtin_amdgcn_mfma_f32_16x16x32_bf16(af[kk], bf, acc, 0, 0, 0);
      }
      float bv = bl1[n * 16 + c];
#pragma unroll
      for (int i = 0; i < 4; i++)
        tile[wrow + quad * 4 + i][n * 16 + c] = f2bf(fmaxf(acc[i] + bv, 0.0f));
    }
  }
  // wave-private rows: no __syncthreads needed (compiler orders LDS w->r via lgkmcnt)

  // ---- stage 2 ----
  {
    bf16x8 af[8];
#pragma unroll
    for (int kk = 0; kk < 8; kk++)
      af[kk] = *(const bf16x8*)&tile[wrow + c][kk * 32 + quad * 8];

#pragma unroll
    for (int n = 0; n < 16; n++) {
      f32x4 acc = {0.f, 0.f, 0.f, 0.f};
#pragma unroll
      for (int kk = 0; kk < 8; kk++) {
        bf16x8 bf = *(const bf16x8*)(Wt2 + ((size_t)(n * 16 + c) * 256 + kk * 32 + quad * 8));
        acc = __builtin_amdgcn_mfma_f32_16x16x32_bf16(af[kk], bf, acc, 0, 0, 0);
      }
      int col = n * 16 + c;                 // wave-uniform n -> uniform branch below
      if (col < 128) {
#pragma unroll
        for (int i = 0; i < 4; i++) {
          int row = row0 + wrow + quad * 4 + i;
          if (row < NN) hW[(size_t)row * DIM + col] = acc[i];
        }
      } else {
        float bv = bl2[col - 128];
#pragma unroll
        for (int i = 0; i < 4; i++) {
          int row = row0 + wrow + quad * 4 + i;
          if (row < NN) dref[(size_t)row * DIM + (col - 128)] = acc[i] + bv;
        }
      }
    }
  }
}

// ---------------- layer-2 scatter: dref[dst] += hW[src] * invdeg[dst] ----------------
__global__ __launch_bounds__(256) void scatter2_kernel(const int* __restrict__ src,
                                                       const int* __restrict__ dst,
                                                       const float* __restrict__ hW,
                                                       const float* __restrict__ invdeg,
                                                       float* __restrict__ dref) {
  int i = blockIdx.x * 256 + threadIdx.x;   // NE*DIM threads, exact grid
  int e = i >> 7;
  int t = i & (DIM - 1);
  int s = src[e];
  int d = dst[e];
  atomicAdd(&dref[(size_t)d * DIM + t], hW[(size_t)s * DIM + t] * invdeg[d]);
}

// ---------------- edge scoring: out[e] = dot(refined[src], refined[dst]) ----------------
__global__ __launch_bounds__(256) void score_kernel(const int* __restrict__ src,
                                                    const int* __restrict__ dst,
                                                    const float* __restrict__ refined,
                                                    float* __restrict__ out) {
  int gid = blockIdx.x * 256 + threadIdx.x;
  int e = gid >> 6;
  int lane = threadIdx.x & 63;
  if (e >= NE) return;
  int s = src[e];
  int d = dst[e];
  float2 a = ((const float2*)(refined + (size_t)s * DIM))[lane];
  float2 b = ((const float2*)(refined + (size_t)d * DIM))[lane];
  float sum = a.x * b.x + a.y * b.y;
#pragma unroll
  for (int off = 1; off < 64; off <<= 1) sum += __shfl_xor(sum, off, 64);
  if (lane == 0) out[e] = sum;
}

extern "C" void kernel_launch(void* const* d_in, const int* in_sizes, int n_in,
                              void* d_out, int out_size, void* d_ws, size_t ws_size,
                              hipStream_t stream) {
  const int* ei    = (const int*)d_in[0];
  const int* src   = ei;
  const int* dst   = ei + NE;
  // d_in[1] = edge_attr (unused by the reference)
  const float* movie = (const float*)d_in[2];
  const float* user  = (const float*)d_in[3];
  const float* Wl1   = (const float*)d_in[4];
  const float* bl1   = (const float*)d_in[5];
  const float* Wr1   = (const float*)d_in[6];
  const float* Wl2   = (const float*)d_in[7];
  const float* bl2   = (const float*)d_in[8];
  const float* Wr2   = (const float*)d_in[9];

  float* out  = (float*)d_out;       // [NE] ratings
  float* dref = out + NE;            // [NN*DIM] refined (also layer-1 accumulator)

  // workspace: invdeg [NN] + hW [NN*DIM] f32 + Wt1/Wt2 [65536 each] bf16  = 77.7 MB
  float* ws     = (float*)d_ws;
  float* invdeg = ws;                         // holds deg first, then 1/max(deg,1)
  float* hW     = invdeg + NN;
  short* Wt1    = (short*)(hW + (size_t)NN * DIM);
  short* Wt2    = Wt1 + 256 * 256;

  hipMemsetAsync(invdeg, 0, (size_t)NN * sizeof(float), stream);
  hipMemsetAsync(dref, 0, (size_t)NN * DIM * sizeof(float), stream);

  deg_kernel<<<(NE + 255) / 256, 256, 0, stream>>>(dst, invdeg);
  invdeg_kernel<<<(NN + 255) / 256, 256, 0, stream>>>(invdeg);
  agg1_kernel<<<NE * DIM / 256, 256, 0, stream>>>(src, dst, movie, user, dref);
  convw_kernel<<<2 * 256 * 256 / 256, 256, 0, stream>>>(Wl1, Wr1, Wl2, Wr2, Wt1, Wt2);
  fused_mfma_kernel<<<(NN + MBLK - 1) / MBLK, 256, 0, stream>>>(
      dref, movie, user, invdeg, Wt1, bl1, Wt2, bl2, hW);
  scatter2_kernel<<<NE * DIM / 256, 256, 0, stream>>>(src, dst, hW, invdeg, dref);
  score_kernel<<<(NE * 64 + 255) / 256, 256, 0, stream>>>(src, dst, dref, out);
}

// Round 4
// 593.565 us; speedup vs baseline: 2.5701x; 1.8103x over previous
//
#include <hip/hip_runtime.h>

#define NMOV 100000
#define NUSR 50000
#define NN   150000
#define DIM  128
#define HID  256
#define NE   500000

#define MBLK 64            // rows per block
#define LDK  264           // LDS row stride in shorts (528 B = 16B-aligned, c/c+8 2-way alias only)
#define NB_SCAN ((NN + 255) / 256)   // 586

typedef __attribute__((ext_vector_type(8))) short bf16x8;
typedef __attribute__((ext_vector_type(4))) float f32x4;

__device__ __forceinline__ short f2bf(float f) {
  union { float f; unsigned u; } v; v.f = f;
  unsigned r = (v.u + 0x7fffu + ((v.u >> 16) & 1u)) >> 16;   // RNE
  return (short)r;
}

// ================= CSR build =================
__global__ __launch_bounds__(256) void deg_kernel(const int* __restrict__ dst,
                                                  int* __restrict__ degi) {
  int e = blockIdx.x * 256 + threadIdx.x;
  if (e < NE) atomicAdd(&degi[dst[e]], 1);
}

// per-block exclusive scan + block sums
__global__ __launch_bounds__(256) void scan1_kernel(const int* __restrict__ degi,
                                                    int* __restrict__ pre,
                                                    int* __restrict__ bsum) {
  __shared__ int s[256];
  int tid = threadIdx.x;
  int i = blockIdx.x * 256 + tid;
  int v = (i < NN) ? degi[i] : 0;
  s[tid] = v;
  __syncthreads();
#pragma unroll
  for (int off = 1; off < 256; off <<= 1) {
    int t = (tid >= off) ? s[tid - off] : 0;
    __syncthreads();
    s[tid] += t;
    __syncthreads();
  }
  if (i < NN) pre[i] = s[tid] - v;
  if (tid == 255) bsum[blockIdx.x] = s[255];
}

// single-block scan of block sums (in-place -> exclusive)
__global__ __launch_bounds__(1024) void scan2_kernel(int* __restrict__ bsum) {
  __shared__ int s[1024];
  int tid = threadIdx.x;
  int v = (tid < NB_SCAN) ? bsum[tid] : 0;
  s[tid] = v;
  __syncthreads();
#pragma unroll
  for (int off = 1; off < 1024; off <<= 1) {
    int t = (tid >= off) ? s[tid - off] : 0;
    __syncthreads();
    s[tid] += t;
    __syncthreads();
  }
  bsum[tid] = s[tid] - v;   // exclusive
}

__global__ __launch_bounds__(256) void scan3_kernel(const int* __restrict__ pre,
                                                    const int* __restrict__ bsum,
                                                    int* __restrict__ rowptr) {
  int i = blockIdx.x * 256 + threadIdx.x;
  if (i < NN) rowptr[i] = pre[i] + bsum[blockIdx.x];
  if (i == 0) rowptr[NN] = NE;
}

__global__ __launch_bounds__(256) void csr_scatter_kernel(const int* __restrict__ src,
                                                          const int* __restrict__ dst,
                                                          const int* __restrict__ rowptr,
                                                          int* __restrict__ cnt,
                                                          int* __restrict__ esrc) {
  int e = blockIdx.x * 256 + threadIdx.x;
  if (e >= NE) return;
  int d = dst[e];
  int pos = rowptr[d] + atomicAdd(&cnt[d], 1);
  esrc[pos] = src[e];
}

// ================= gather-mean aggregations (no atomics) =================
// one wave per node; 64 lanes x float2 = 128 floats (coalesced row reads)
__global__ __launch_bounds__(256) void gather1_kernel(const int* __restrict__ rowptr,
                                                      const int* __restrict__ esrc,
                                                      const float* __restrict__ movie,
                                                      const float* __restrict__ user,
                                                      float* __restrict__ agg) {
  int node = (blockIdx.x * 256 + threadIdx.x) >> 6;
  int lane = threadIdx.x & 63;
  if (node >= NN) return;
  int b = rowptr[node], e = rowptr[node + 1];
  float2 acc = make_float2(0.f, 0.f);
  for (int j = b; j < e; j++) {
    int s = esrc[j];
    const float* row = (s < NMOV) ? (movie + (size_t)s * DIM)
                                  : (user + (size_t)(s - NMOV) * DIM);
    float2 v = ((const float2*)row)[lane];
    acc.x += v.x; acc.y += v.y;
  }
  float inv = 1.0f / fmaxf((float)(e - b), 1.0f);
  float2 o; o.x = acc.x * inv; o.y = acc.y * inv;
  ((float2*)(agg + (size_t)node * DIM))[lane] = o;
}

// dref[node] += mean(hW[src in N(node)])
__global__ __launch_bounds__(256) void gather2_kernel(const int* __restrict__ rowptr,
                                                      const int* __restrict__ esrc,
                                                      const float* __restrict__ hW,
                                                      float* __restrict__ dref) {
  int node = (blockIdx.x * 256 + threadIdx.x) >> 6;
  int lane = threadIdx.x & 63;
  if (node >= NN) return;
  int b = rowptr[node], e = rowptr[node + 1];
  float2 acc = make_float2(0.f, 0.f);
  for (int j = b; j < e; j++) {
    int s = esrc[j];
    float2 v = ((const float2*)(hW + (size_t)s * DIM))[lane];
    acc.x += v.x; acc.y += v.y;
  }
  float inv = 1.0f / fmaxf((float)(e - b), 1.0f);
  float2* p = (float2*)(dref + (size_t)node * DIM);
  float2 cur = p[lane];
  cur.x += acc.x * inv; cur.y += acc.y * inv;
  p[lane] = cur;
}

// ================= weight swizzle: bf16, MFMA-fragment-linear =================
// frag (stage, n, kk) = 64 lanes x 8 shorts contiguous (1 KB), lane=(quad<<4)|c holds
// B[k=kk*32+quad*8+j][ncol=n*16+c].  Stage1: k<128->Wl1 else Wr1 (concat K).
// Stage2: ncol<128->Wl2 (hW cols) else Wr2 (dref cols).
__global__ __launch_bounds__(256) void convw_kernel(const float* __restrict__ Wl1,
                                                    const float* __restrict__ Wr1,
                                                    const float* __restrict__ Wl2,
                                                    const float* __restrict__ Wr2,
                                                    short* __restrict__ Wf1,
                                                    short* __restrict__ Wf2) {
  int t = blockIdx.x * 256 + threadIdx.x;   // 2*16*8*64 = 16384 threads
  int stage = t >> 13;
  int r = t & 8191;
  int n    = r >> 9;
  int kk   = (r >> 6) & 7;
  int lane = r & 63;
  int ncol  = n * 16 + (lane & 15);
  int kbase = kk * 32 + (lane >> 4) * 8;
  short vals[8];
#pragma unroll
  for (int jj = 0; jj < 8; jj++) {
    int k = kbase + jj;
    float v;
    if (stage == 0)
      v = (k < 128) ? Wl1[(size_t)k * HID + ncol] : Wr1[(size_t)(k - 128) * HID + ncol];
    else
      v = (ncol < 128) ? Wl2[(size_t)k * DIM + ncol] : Wr2[(size_t)k * DIM + (ncol - 128)];
    vals[jj] = f2bf(v);
  }
  short* out = (stage == 0 ? Wf1 : Wf2) + ((size_t)(n * 8 + kk) << 9) + lane * 8;
  *(short4*)(out)     = make_short4(vals[0], vals[1], vals[2], vals[3]);
  *(short4*)(out + 4) = make_short4(vals[4], vals[5], vals[6], vals[7]);
}

// ================= fused MFMA: both GEMMs, h stays in LDS =================
// Block = 64 rows, 4 waves. Wave (rq = wv&1, ch = wv>>1) owns rows rq*32..+32,
// cols ch*128..+128 (8 n-tiles), 2 row-groups sharing every B fragment.
__global__ __launch_bounds__(256) void fused_mfma_kernel(
    float* __restrict__ dref, const float* __restrict__ movie,
    const float* __restrict__ user,
    const short* __restrict__ Wf1, const float* __restrict__ bl1,
    const short* __restrict__ Wf2, const float* __restrict__ bl2,
    float* __restrict__ hW) {
  __shared__ short tile[MBLK][LDK];
  const int tid = threadIdx.x;
  const int row0 = blockIdx.x * MBLK;

  // stage A_cat = [agg(mean) | x] as bf16
  for (int idx = tid; idx < MBLK * 64; idx += 256) {
    int r  = idx >> 6;
    int c4 = idx & 63;
    int row = row0 + r;
    float4 v = make_float4(0.f, 0.f, 0.f, 0.f);
    if (row < NN) {
      if (c4 < 32) {
        v = ((const float4*)(dref + (size_t)row * DIM))[c4];
      } else {
        const float* xrow = (row < NMOV) ? (movie + (size_t)row * DIM)
                                         : (user + (size_t)(row - NMOV) * DIM);
        v = ((const float4*)xrow)[c4 - 32];
      }
    }
    short4 s4;
    s4.x = f2bf(v.x); s4.y = f2bf(v.y); s4.z = f2bf(v.z); s4.w = f2bf(v.w);
    *(short4*)&tile[r][c4 * 4] = s4;
  }
  __syncthreads();

  const int lane = tid & 63;
  const int wv   = tid >> 6;
  const int c    = lane & 15;
  const int quad = lane >> 4;
  const int wrow = (wv & 1) * 32;     // row half
  const int ch   = wv >> 1;           // col half

  // ---- stage 1: h = relu(A_cat @ W1 + bl1) -> LDS ----
  {
    bf16x8 af[2][8];
#pragma unroll
    for (int rg = 0; rg < 2; rg++)
#pragma unroll
      for (int kk = 0; kk < 8; kk++)
        af[rg][kk] = *(const bf16x8*)&tile[wrow + rg * 16 + c][kk * 32 + quad * 8];

#pragma unroll 2
    for (int nn = 0; nn < 8; nn++) {
      int n = ch * 8 + nn;
      const short* wp = Wf1 + ((size_t)(n * 8) << 9) + lane * 8;
      f32x4 a0 = {0.f, 0.f, 0.f, 0.f}, a1 = {0.f, 0.f, 0.f, 0.f};
#pragma unroll
      for (int kk = 0; kk < 8; kk++) {
        bf16x8 bf = *(const bf16x8*)(wp + ((size_t)kk << 9));
        a0 = __builtin_amdgcn_mfma_f32_16x16x32_bf16(af[0][kk], bf, a0, 0, 0, 0);
        a1 = __builtin_amdgcn_mfma_f32_16x16x32_bf16(af[1][kk], bf, a1, 0, 0, 0);
      }
      float bv = bl1[n * 16 + c];
#pragma unroll
      for (int i = 0; i < 4; i++) {
        tile[wrow + quad * 4 + i][n * 16 + c]      = f2bf(fmaxf(a0[i] + bv, 0.0f));
        tile[wrow + 16 + quad * 4 + i][n * 16 + c] = f2bf(fmaxf(a1[i] + bv, 0.0f));
      }
    }
  }
  __syncthreads();

  // ---- stage 2: [hW | dref] = h @ W2 (+bl2 on dref half) ----
  {
    bf16x8 af[2][8];
#pragma unroll
    for (int rg = 0; rg < 2; rg++)
#pragma unroll
      for (int kk = 0; kk < 8; kk++)
        af[rg][kk] = *(const bf16x8*)&tile[wrow + rg * 16 + c][kk * 32 + quad * 8];

#pragma unroll 2
    for (int nn = 0; nn < 8; nn++) {
      int n = ch * 8 + nn;
      const short* wp = Wf2 + ((size_t)(n * 8) << 9) + lane * 8;
      f32x4 a0 = {0.f, 0.f, 0.f, 0.f}, a1 = {0.f, 0.f, 0.f, 0.f};
#pragma unroll
      for (int kk = 0; kk < 8; kk++) {
        bf16x8 bf = *(const bf16x8*)(wp + ((size_t)kk << 9));
        a0 = __builtin_amdgcn_mfma_f32_16x16x32_bf16(af[0][kk], bf, a0, 0, 0, 0);
        a1 = __builtin_amdgcn_mfma_f32_16x16x32_bf16(af[1][kk], bf, a1, 0, 0, 0);
      }
      int col = n * 16 + c;
      if (ch == 0) {          // wave-uniform: cols 0..127 -> hW
#pragma unroll
        for (int i = 0; i < 4; i++) {
          int r0 = row0 + wrow + quad * 4 + i;
          int r1 = r0 + 16;
          if (r0 < NN) hW[(size_t)r0 * DIM + col] = a0[i];
          if (r1 < NN) hW[(size_t)r1 * DIM + col] = a1[i];
        }
      } else {                // cols 128..255 -> dref (+bias)
        float bv = bl2[col - 128];
#pragma unroll
        for (int i = 0; i < 4; i++) {
          int r0 = row0 + wrow + quad * 4 + i;
          int r1 = r0 + 16;
          if (r0 < NN) dref[(size_t)r0 * DIM + (col - 128)] = a0[i] + bv;
          if (r1 < NN) dref[(size_t)r1 * DIM + (col - 128)] = a1[i] + bv;
        }
      }
    }
  }
}

// ================= edge scoring =================
__global__ __launch_bounds__(256) void score_kernel(const int* __restrict__ src,
                                                    const int* __restrict__ dst,
                                                    const float* __restrict__ refined,
                                                    float* __restrict__ out) {
  int gid = blockIdx.x * 256 + threadIdx.x;
  int e = gid >> 6;
  int lane = threadIdx.x & 63;
  if (e >= NE) return;
  int s = src[e];
  int d = dst[e];
  float2 a = ((const float2*)(refined + (size_t)s * DIM))[lane];
  float2 b = ((const float2*)(refined + (size_t)d * DIM))[lane];
  float sum = a.x * b.x + a.y * b.y;
#pragma unroll
  for (int off = 1; off < 64; off <<= 1) sum += __shfl_xor(sum, off, 64);
  if (lane == 0) out[e] = sum;
}

extern "C" void kernel_launch(void* const* d_in, const int* in_sizes, int n_in,
                              void* d_out, int out_size, void* d_ws, size_t ws_size,
                              hipStream_t stream) {
  const int* ei    = (const int*)d_in[0];
  const int* src   = ei;
  const int* dst   = ei + NE;
  // d_in[1] = edge_attr (unused by the reference)
  const float* movie = (const float*)d_in[2];
  const float* user  = (const float*)d_in[3];
  const float* Wl1   = (const float*)d_in[4];
  const float* bl1   = (const float*)d_in[5];
  const float* Wr1   = (const float*)d_in[6];
  const float* Wl2   = (const float*)d_in[7];
  const float* bl2   = (const float*)d_in[8];
  const float* Wr2   = (const float*)d_in[9];

  float* out  = (float*)d_out;       // [NE] ratings
  float* dref = out + NE;            // [NN*DIM] refined (also layer-1 mean-agg buffer)

  // workspace layout (ints then floats/shorts), ~81.5 MB
  int* degi   = (int*)d_ws;                    // [NN]   (zeroed)
  int* cnt    = degi + NN;                     // [NN]   (zeroed)
  int* pre    = cnt + NN;                      // [NN]
  int* bsum   = pre + NN;                      // [1024]
  int* rowptr = bsum + 1024;                   // [NN+1]
  int* esrc   = rowptr + NN + 1;               // [NE]
  float* hW   = (float*)(esrc + NE + 1);       // [NN*DIM]
  short* Wf1  = (short*)(hW + (size_t)NN * DIM);  // [65536]
  short* Wf2  = Wf1 + 65536;                      // [65536]

  hipMemsetAsync(degi, 0, (size_t)2 * NN * sizeof(int), stream);

  deg_kernel<<<(NE + 255) / 256, 256, 0, stream>>>(dst, degi);
  scan1_kernel<<<NB_SCAN, 256, 0, stream>>>(degi, pre, bsum);
  scan2_kernel<<<1, 1024, 0, stream>>>(bsum);
  scan3_kernel<<<NB_SCAN, 256, 0, stream>>>(pre, bsum, rowptr);
  csr_scatter_kernel<<<(NE + 255) / 256, 256, 0, stream>>>(src, dst, rowptr, cnt, esrc);
  convw_kernel<<<16384 / 256, 256, 0, stream>>>(Wl1, Wr1, Wl2, Wr2, Wf1, Wf2);
  gather1_kernel<<<NN * 64 / 256, 256, 0, stream>>>(rowptr, esrc, movie, user, dref);
  fused_mfma_kernel<<<(NN + MBLK - 1) / MBLK, 256, 0, stream>>>(
      dref, movie, user, Wf1, bl1, Wf2, bl2, hW);
  gather2_kernel<<<NN * 64 / 256, 256, 0, stream>>>(rowptr, esrc, hW, dref);
  score_kernel<<<NE * 64 / 256, 256, 0, stream>>>(src, dst, dref, out);
}

// Round 6
// 471.736 us; speedup vs baseline: 3.2339x; 1.2583x over previous
//
#include <hip/hip_runtime.h>

#define NMOV 100000
#define NUSR 50000
#define NN   150000
#define DIM  128
#define HID  256
#define NE   500000

#define MBLK 64            // rows per block
#define LDK  264           // LDS row stride in shorts for the A/h tile
#define HWS  136           // LDS row stride (shorts) for hW epilogue staging (16B-aligned rows)
#define NB_SCAN ((NN + 255) / 256)   // 586

typedef __attribute__((ext_vector_type(8))) short bf16x8;
typedef __attribute__((ext_vector_type(4))) float f32x4;

__device__ __forceinline__ short f2bf(float f) {
  union { float f; unsigned u; } v; v.f = f;
  unsigned r = (v.u + 0x7fffu + ((v.u >> 16) & 1u)) >> 16;   // RNE
  return (short)r;
}
__device__ __forceinline__ float bf2f(short s) {
  union { unsigned u; float f; } v;
  v.u = ((unsigned)(unsigned short)s) << 16;
  return v.f;
}

// ================= CSR build =================
__global__ __launch_bounds__(256) void deg_kernel(const int* __restrict__ dst,
                                                  int* __restrict__ degi) {
  int e = blockIdx.x * 256 + threadIdx.x;
  if (e < NE) atomicAdd(&degi[dst[e]], 1);
}

__global__ __launch_bounds__(256) void scan1_kernel(const int* __restrict__ degi,
                                                    int* __restrict__ pre,
                                                    int* __restrict__ bsum) {
  __shared__ int s[256];
  int tid = threadIdx.x;
  int i = blockIdx.x * 256 + tid;
  int v = (i < NN) ? degi[i] : 0;
  s[tid] = v;
  __syncthreads();
#pragma unroll
  for (int off = 1; off < 256; off <<= 1) {
    int t = (tid >= off) ? s[tid - off] : 0;
    __syncthreads();
    s[tid] += t;
    __syncthreads();
  }
  if (i < NN) pre[i] = s[tid] - v;
  if (tid == 255) bsum[blockIdx.x] = s[255];
}

__global__ __launch_bounds__(1024) void scan2_kernel(int* __restrict__ bsum) {
  __shared__ int s[1024];
  int tid = threadIdx.x;
  int v = (tid < NB_SCAN) ? bsum[tid] : 0;
  s[tid] = v;
  __syncthreads();
#pragma unroll
  for (int off = 1; off < 1024; off <<= 1) {
    int t = (tid >= off) ? s[tid - off] : 0;
    __syncthreads();
    s[tid] += t;
    __syncthreads();
  }
  bsum[tid] = s[tid] - v;   // exclusive
}

__global__ __launch_bounds__(256) void scan3_kernel(const int* __restrict__ pre,
                                                    const int* __restrict__ bsum,
                                                    int* __restrict__ rowptr) {
  int i = blockIdx.x * 256 + threadIdx.x;
  if (i < NN) rowptr[i] = pre[i] + bsum[blockIdx.x];
  if (i == 0) rowptr[NN] = NE;
}

__global__ __launch_bounds__(256) void csr_scatter_kernel(const int* __restrict__ src,
                                                          const int* __restrict__ dst,
                                                          const int* __restrict__ rowptr,
                                                          int* __restrict__ cnt,
                                                          int* __restrict__ esrc) {
  int e = blockIdx.x * 256 + threadIdx.x;
  if (e >= NE) return;
  int d = dst[e];
  int pos = rowptr[d] + atomicAdd(&cnt[d], 1);
  esrc[pos] = src[e];
}

// ================= bf16 conversion of node features =================
__global__ __launch_bounds__(256) void convx_kernel(const float* __restrict__ movie,
                                                    const float* __restrict__ user,
                                                    short* __restrict__ xb) {
  int c = blockIdx.x * 256 + threadIdx.x;        // chunk of 8
  if (c >= NN * DIM / 8) return;
  size_t base = (size_t)c * 8;
  const float* srcp = (base < (size_t)NMOV * DIM) ? (movie + base)
                                                  : (user + (base - (size_t)NMOV * DIM));
  float4 v0 = ((const float4*)srcp)[0];
  float4 v1 = ((const float4*)srcp)[1];
  short4 s0 = make_short4(f2bf(v0.x), f2bf(v0.y), f2bf(v0.z), f2bf(v0.w));
  short4 s1 = make_short4(f2bf(v1.x), f2bf(v1.y), f2bf(v1.z), f2bf(v1.w));
  *(short4*)(xb + base)     = s0;
  *(short4*)(xb + base + 4) = s1;
}

// ================= weight swizzle: bf16, MFMA-fragment-linear =================
__global__ __launch_bounds__(256) void convw_kernel(const float* __restrict__ Wl1,
                                                    const float* __restrict__ Wr1,
                                                    const float* __restrict__ Wl2,
                                                    const float* __restrict__ Wr2,
                                                    short* __restrict__ Wf1,
                                                    short* __restrict__ Wf2) {
  int t = blockIdx.x * 256 + threadIdx.x;   // 2*16*8*64 = 16384 threads
  int stage = t >> 13;
  int r = t & 8191;
  int n    = r >> 9;
  int kk   = (r >> 6) & 7;
  int lane = r & 63;
  int ncol  = n * 16 + (lane & 15);
  int kbase = kk * 32 + (lane >> 4) * 8;
  short vals[8];
#pragma unroll
  for (int jj = 0; jj < 8; jj++) {
    int k = kbase + jj;
    float v;
    if (stage == 0)
      v = (k < 128) ? Wl1[(size_t)k * HID + ncol] : Wr1[(size_t)(k - 128) * HID + ncol];
    else
      v = (ncol < 128) ? Wl2[(size_t)k * DIM + ncol] : Wr2[(size_t)k * DIM + (ncol - 128)];
    vals[jj] = f2bf(v);
  }
  short* outp = (stage == 0 ? Wf1 : Wf2) + ((size_t)(n * 8 + kk) << 9) + lane * 8;
  *(short4*)(outp)     = make_short4(vals[0], vals[1], vals[2], vals[3]);
  *(short4*)(outp + 4) = make_short4(vals[4], vals[5], vals[6], vals[7]);
}

// ================= gather1: aggb[node] = bf16(mean of xb[src rows]) =================
__global__ __launch_bounds__(256) void gather1_kernel(const int* __restrict__ rowptr,
                                                      const int* __restrict__ esrc,
                                                      const short* __restrict__ xb,
                                                      short* __restrict__ aggb) {
  int t = blockIdx.x * 256 + threadIdx.x;
  int node = t >> 4, l = t & 15;
  if (node >= NN) return;
  int b = rowptr[node], e = rowptr[node + 1];
  float acc[8] = {0.f, 0.f, 0.f, 0.f, 0.f, 0.f, 0.f, 0.f};
  int j = b;
  for (; j + 1 < e; j += 2) {
    int s0 = esrc[j], s1 = esrc[j + 1];
    const short* r0 = xb + (size_t)s0 * DIM;
    const short* r1 = xb + (size_t)s1 * DIM;
    short4 p0 = *(const short4*)(r0 + l * 4);
    short4 q0 = *(const short4*)(r0 + 64 + l * 4);
    short4 p1 = *(const short4*)(r1 + l * 4);
    short4 q1 = *(const short4*)(r1 + 64 + l * 4);
    acc[0] += bf2f(p0.x) + bf2f(p1.x); acc[1] += bf2f(p0.y) + bf2f(p1.y);
    acc[2] += bf2f(p0.z) + bf2f(p1.z); acc[3] += bf2f(p0.w) + bf2f(p1.w);
    acc[4] += bf2f(q0.x) + bf2f(q1.x); acc[5] += bf2f(q0.y) + bf2f(q1.y);
    acc[6] += bf2f(q0.z) + bf2f(q1.z); acc[7] += bf2f(q0.w) + bf2f(q1.w);
  }
  if (j < e) {
    int s0 = esrc[j];
    const short* r0 = xb + (size_t)s0 * DIM;
    short4 p0 = *(const short4*)(r0 + l * 4);
    short4 q0 = *(const short4*)(r0 + 64 + l * 4);
    acc[0] += bf2f(p0.x); acc[1] += bf2f(p0.y); acc[2] += bf2f(p0.z); acc[3] += bf2f(p0.w);
    acc[4] += bf2f(q0.x); acc[5] += bf2f(q0.y); acc[6] += bf2f(q0.z); acc[7] += bf2f(q0.w);
  }
  float inv = 1.0f / fmaxf((float)(e - b), 1.0f);
  short4 o0 = make_short4(f2bf(acc[0] * inv), f2bf(acc[1] * inv),
                          f2bf(acc[2] * inv), f2bf(acc[3] * inv));
  short4 o1 = make_short4(f2bf(acc[4] * inv), f2bf(acc[5] * inv),
                          f2bf(acc[6] * inv), f2bf(acc[7] * inv));
  *(short4*)(aggb + (size_t)node * DIM + l * 4)      = o0;
  *(short4*)(aggb + (size_t)node * DIM + 64 + l * 4) = o1;
}

// ================= fused MFMA: both GEMMs, h stays in LDS =================
// ab_hw: aggb on input (this block's rows read at staging), hWb on output
// (same rows overwritten at epilogue) — block-private rows, safe alias.
__global__ __launch_bounds__(256) void fused_mfma_kernel(
    const short* __restrict__ xb, short* ab_hw,
    const short* __restrict__ Wf1, const float* __restrict__ bl1,
    const short* __restrict__ Wf2, const float* __restrict__ bl2,
    float* __restrict__ dref) {
  __shared__ __align__(16) short tile[MBLK][LDK];
  const int tid = threadIdx.x;
  const int row0 = blockIdx.x * MBLK;

  // stage A_cat = [aggb | xb] bf16, 16B chunks, no conversion needed
  for (int idx = tid; idx < MBLK * 32; idx += 256) {
    int r   = idx >> 5;
    int c16 = idx & 31;
    int row = row0 + r;
    int col = c16 * 8;
    int4 v = make_int4(0, 0, 0, 0);
    if (row < NN) {
      const short* srcp = (col < DIM) ? (ab_hw + (size_t)row * DIM + col)
                                      : (xb + (size_t)row * DIM + (col - DIM));
      v = *(const int4*)srcp;
    }
    *(int4*)&tile[r][col] = v;
  }
  __syncthreads();

  const int lane = tid & 63;
  const int wv   = tid >> 6;
  const int c    = lane & 15;
  const int quad = lane >> 4;
  const int wrow = (wv & 1) * 32;     // row half
  const int ch   = wv >> 1;           // col half

  // ---- stage 1: h = relu(A_cat @ W1 + bl1) -> LDS ----
  {
    bf16x8 af[2][8];
#pragma unroll
    for (int rg = 0; rg < 2; rg++)
#pragma unroll
      for (int kk = 0; kk < 8; kk++)
        af[rg][kk] = *(const bf16x8*)&tile[wrow + rg * 16 + c][kk * 32 + quad * 8];

#pragma unroll 2
    for (int nn = 0; nn < 8; nn++) {
      int n = ch * 8 + nn;
      const short* wp = Wf1 + ((size_t)(n * 8) << 9) + lane * 8;
      f32x4 a0 = {0.f, 0.f, 0.f, 0.f}, a1 = {0.f, 0.f, 0.f, 0.f};
#pragma unroll
      for (int kk = 0; kk < 8; kk++) {
        bf16x8 bf = *(const bf16x8*)(wp + ((size_t)kk << 9));
        a0 = __builtin_amdgcn_mfma_f32_16x16x32_bf16(af[0][kk], bf, a0, 0, 0, 0);
        a1 = __builtin_amdgcn_mfma_f32_16x16x32_bf16(af[1][kk], bf, a1, 0, 0, 0);
      }
      float bv = bl1[n * 16 + c];
#pragma unroll
      for (int i = 0; i < 4; i++) {
        tile[wrow + quad * 4 + i][n * 16 + c]      = f2bf(fmaxf(a0[i] + bv, 0.0f));
        tile[wrow + 16 + quad * 4 + i][n * 16 + c] = f2bf(fmaxf(a1[i] + bv, 0.0f));
      }
    }
  }
  __syncthreads();

  // ---- stage 2: hW (cols 0..127, ch=0) via LDS; dref (cols 128..255, ch=1) direct ----
  bf16x8 af[2][8];
#pragma unroll
  for (int rg = 0; rg < 2; rg++)
#pragma unroll
    for (int kk = 0; kk < 8; kk++)
      af[rg][kk] = *(const bf16x8*)&tile[wrow + rg * 16 + c][kk * 32 + quad * 8];
  __syncthreads();                     // all waves done reading tile -> safe to reuse

  short* hw_s = &tile[0][0];           // [64][HWS] bf16 staging for hW half

#pragma unroll 2
  for (int nn = 0; nn < 8; nn++) {
    int n = ch * 8 + nn;
    const short* wp = Wf2 + ((size_t)(n * 8) << 9) + lane * 8;
    f32x4 a0 = {0.f, 0.f, 0.f, 0.f}, a1 = {0.f, 0.f, 0.f, 0.f};
#pragma unroll
    for (int kk = 0; kk < 8; kk++) {
      bf16x8 bf = *(const bf16x8*)(wp + ((size_t)kk << 9));
      a0 = __builtin_amdgcn_mfma_f32_16x16x32_bf16(af[0][kk], bf, a0, 0, 0, 0);
      a1 = __builtin_amdgcn_mfma_f32_16x16x32_bf16(af[1][kk], bf, a1, 0, 0, 0);
    }
    int col = n * 16 + c;
    if (ch == 0) {                     // wave-uniform branch
#pragma unroll
      for (int i = 0; i < 4; i++) {
        hw_s[(wrow + quad * 4 + i) * HWS + col]      = f2bf(a0[i]);
        hw_s[(wrow + 16 + quad * 4 + i) * HWS + col] = f2bf(a1[i]);
      }
    } else {
      float bv = bl2[col - 128];
#pragma unroll
      for (int i = 0; i < 4; i++) {
        int r0 = row0 + wrow + quad * 4 + i;
        int r1 = r0 + 16;
        if (r0 < NN) dref[(size_t)r0 * DIM + (col - 128)] = a0[i] + bv;
        if (r1 < NN) dref[(size_t)r1 * DIM + (col - 128)] = a1[i] + bv;
      }
    }
  }
  __syncthreads();

  // stream hW out coalesced (full 256B bf16 rows = 16 int4 chunks per row)
  for (int idx = tid; idx < MBLK * 16; idx += 256) {
    int r  = idx >> 4;
    int c8 = idx & 15;
    int row = row0 + r;
    if (row < NN) {
      int4 v = *(const int4*)&hw_s[r * HWS + c8 * 8];
      *(int4*)(ab_hw + (size_t)row * DIM + c8 * 8) = v;
    }
  }
}

// ================= gather2: dref[node] += mean(hWb[src]); drefb = bf16(dref) ==========
__global__ __launch_bounds__(256) void gather2_kernel(const int* __restrict__ rowptr,
                                                      const int* __restrict__ esrc,
                                                      const short* __restrict__ hWb,
                                                      float* __restrict__ dref,
                                                      short* __restrict__ drefb) {
  int t = blockIdx.x * 256 + threadIdx.x;
  int node = t >> 4, l = t & 15;
  if (node >= NN) return;
  int b = rowptr[node], e = rowptr[node + 1];
  float acc[8] = {0.f, 0.f, 0.f, 0.f, 0.f, 0.f, 0.f, 0.f};
  int j = b;
  for (; j + 1 < e; j += 2) {
    int s0 = esrc[j], s1 = esrc[j + 1];
    const short* r0 = hWb + (size_t)s0 * DIM;
    const short* r1 = hWb + (size_t)s1 * DIM;
    short4 p0 = *(const short4*)(r0 + l * 4);
    short4 q0 = *(const short4*)(r0 + 64 + l * 4);
    short4 p1 = *(const short4*)(r1 + l * 4);
    short4 q1 = *(const short4*)(r1 + 64 + l * 4);
    acc[0] += bf2f(p0.x) + bf2f(p1.x); acc[1] += bf2f(p0.y) + bf2f(p1.y);
    acc[2] += bf2f(p0.z) + bf2f(p1.z); acc[3] += bf2f(p0.w) + bf2f(p1.w);
    acc[4] += bf2f(q0.x) + bf2f(q1.x); acc[5] += bf2f(q0.y) + bf2f(q1.y);
    acc[6] += bf2f(q0.z) + bf2f(q1.z); acc[7] += bf2f(q0.w) + bf2f(q1.w);
  }
  if (j < e) {
    int s0 = esrc[j];
    const short* r0 = hWb + (size_t)s0 * DIM;
    short4 p0 = *(const short4*)(r0 + l * 4);
    short4 q0 = *(const short4*)(r0 + 64 + l * 4);
    acc[0] += bf2f(p0.x); acc[1] += bf2f(p0.y); acc[2] += bf2f(p0.z); acc[3] += bf2f(p0.w);
    acc[4] += bf2f(q0.x); acc[5] += bf2f(q0.y); acc[6] += bf2f(q0.z); acc[7] += bf2f(q0.w);
  }
  float inv = 1.0f / fmaxf((float)(e - b), 1.0f);
  float* dr = dref + (size_t)node * DIM;
  float4 c0 = *(float4*)(dr + l * 4);
  float4 c1 = *(float4*)(dr + 64 + l * 4);
  c0.x += acc[0] * inv; c0.y += acc[1] * inv; c0.z += acc[2] * inv; c0.w += acc[3] * inv;
  c1.x += acc[4] * inv; c1.y += acc[5] * inv; c1.z += acc[6] * inv; c1.w += acc[7] * inv;
  *(float4*)(dr + l * 4)      = c0;
  *(float4*)(dr + 64 + l * 4) = c1;
  short4 o0 = make_short4(f2bf(c0.x), f2bf(c0.y), f2bf(c0.z), f2bf(c0.w));
  short4 o1 = make_short4(f2bf(c1.x), f2bf(c1.y), f2bf(c1.z), f2bf(c1.w));
  *(short4*)(drefb + (size_t)node * DIM + l * 4)      = o0;
  *(short4*)(drefb + (size_t)node * DIM + 64 + l * 4) = o1;
}

// ================= edge scoring from bf16 shadow =================
__global__ __launch_bounds__(256) void score_kernel(const int* __restrict__ src,
                                                    const int* __restrict__ dst,
                                                    const short* __restrict__ drefb,
                                                    float* __restrict__ out) {
  int t = blockIdx.x * 256 + threadIdx.x;
  int e = t >> 4, l = t & 15;
  if (e >= NE) return;
  int s = src[e], d = dst[e];
  const short* ra = drefb + (size_t)s * DIM;
  const short* rb = drefb + (size_t)d * DIM;
  short4 a0 = *(const short4*)(ra + l * 4);
  short4 a1 = *(const short4*)(ra + 64 + l * 4);
  short4 b0 = *(const short4*)(rb + l * 4);
  short4 b1 = *(const short4*)(rb + 64 + l * 4);
  float sum = bf2f(a0.x) * bf2f(b0.x) + bf2f(a0.y) * bf2f(b0.y) +
              bf2f(a0.z) * bf2f(b0.z) + bf2f(a0.w) * bf2f(b0.w) +
              bf2f(a1.x) * bf2f(b1.x) + bf2f(a1.y) * bf2f(b1.y) +
              bf2f(a1.z) * bf2f(b1.z) + bf2f(a1.w) * bf2f(b1.w);
#pragma unroll
  for (int off = 1; off < 16; off <<= 1) sum += __shfl_xor(sum, off, 16);
  if (l == 0) out[e] = sum;
}

extern "C" void kernel_launch(void* const* d_in, const int* in_sizes, int n_in,
                              void* d_out, int out_size, void* d_ws, size_t ws_size,
                              hipStream_t stream) {
  const int* ei    = (const int*)d_in[0];
  const int* src   = ei;
  const int* dst   = ei + NE;
  // d_in[1] = edge_attr (unused by the reference)
  const float* movie = (const float*)d_in[2];
  const float* user  = (const float*)d_in[3];
  const float* Wl1   = (const float*)d_in[4];
  const float* bl1   = (const float*)d_in[5];
  const float* Wr1   = (const float*)d_in[6];
  const float* Wl2   = (const float*)d_in[7];
  const float* bl2   = (const float*)d_in[8];
  const float* Wr2   = (const float*)d_in[9];

  float* out  = (float*)d_out;       // [NE] ratings
  float* dref = out + NE;            // [NN*DIM] refined (f32 output)

  // workspace (~81.6 MB): ints | xb(+drefb alias) | aggb(+hWb alias) | Wf1 | Wf2
  int* degi   = (int*)d_ws;                    // [NN] (zeroed)
  int* cnt    = degi + NN;                     // [NN] (zeroed)
  int* pre    = cnt + NN;                      // [NN]
  int* bsum   = pre + NN;                      // [1024]
  int* rowptr = bsum + 1024;                   // [NN+1]
  int* esrc   = rowptr + NN + 1;               // [NE]
  short* xb   = (short*)(((uintptr_t)(esrc + NE) + 15) & ~(uintptr_t)15);  // [NN*DIM] bf16
  short* aggb = xb + (size_t)NN * DIM;         // [NN*DIM] bf16 (later reused as hWb)
  short* Wf1  = aggb + (size_t)NN * DIM;       // [65536]
  short* Wf2  = Wf1 + 65536;                   // [65536]
  short* hWb   = aggb;                         // alias: fused overwrites its own rows
  short* drefb = xb;                           // alias: xb dead after fused

  hipMemsetAsync(degi, 0, (size_t)2 * NN * sizeof(int), stream);

  deg_kernel<<<(NE + 255) / 256, 256, 0, stream>>>(dst, degi);
  scan1_kernel<<<NB_SCAN, 256, 0, stream>>>(degi, pre, bsum);
  scan2_kernel<<<1, 1024, 0, stream>>>(bsum);
  scan3_kernel<<<NB_SCAN, 256, 0, stream>>>(pre, bsum, rowptr);
  csr_scatter_kernel<<<(NE + 255) / 256, 256, 0, stream>>>(src, dst, rowptr, cnt, esrc);
  convx_kernel<<<NN * DIM / 8 / 256, 256, 0, stream>>>(movie, user, xb);
  convw_kernel<<<16384 / 256, 256, 0, stream>>>(Wl1, Wr1, Wl2, Wr2, Wf1, Wf2);
  gather1_kernel<<<NN * 16 / 256, 256, 0, stream>>>(rowptr, esrc, xb, aggb);
  fused_mfma_kernel<<<(NN + MBLK - 1) / MBLK, 256, 0, stream>>>(
      xb, aggb, Wf1, bl1, Wf2, bl2, dref);
  gather2_kernel<<<NN * 16 / 256, 256, 0, stream>>>(rowptr, esrc, hWb, dref, drefb);
  score_kernel<<<NE * 16 / 256, 256, 0, stream>>>(src, dst, drefb, out);
}